// Round 7
// baseline (134.493 us; speedup 1.0000x reference)
//
#include <hip/hip_runtime.h>
#include <hip/hip_bf16.h>
#include <stdint.h>

// HausdorffLoss: N=M=4096, D=1024 fp32 in, scalar fp32 out.
// R7: fp8(e4m3) MFMA GEMM, 128x256 tile, 512 blocks (2 blocks/CU),
// 3-buffer LDS ring (72KB), quadrant-phase schedule, counted vmcnt(3),
// fused fence-free last-block reduction. Prepass: fp32->fp8 + norms.

#define NPTS 4096
#define MPTS 4096
#define DDIM 1024

typedef __attribute__((ext_vector_type(4))) float f32x4;

__device__ __forceinline__ void gl_lds16(const void* g, void* l) {
    __builtin_amdgcn_global_load_lds(
        (const __attribute__((address_space(1))) unsigned int*)g,
        (__attribute__((address_space(3))) unsigned int*)l, 16, 0, 0);
}

// ---------------- prepass: fp32 -> fp8 e4m3 + row squared norms ------------
__global__ __launch_bounds__(256) void prepass_kernel(
    const float* __restrict__ s1, const float* __restrict__ s2,
    unsigned char* __restrict__ a8, unsigned char* __restrict__ b8,
    float* __restrict__ norms, unsigned int* __restrict__ mins,
    unsigned int* __restrict__ ctr) {
    const int row = blockIdx.x * 4 + (threadIdx.x >> 6);
    const int lane = threadIdx.x & 63;
    if (blockIdx.x == 0 && threadIdx.x == 0) ctr[0] = 0u;
    const float* src;
    unsigned char* dst;
    if (row < NPTS) { src = s1 + (size_t)row * DDIM; dst = a8 + (size_t)row * DDIM; }
    else            { src = s2 + (size_t)(row - NPTS) * DDIM; dst = b8 + (size_t)(row - NPTS) * DDIM; }
    float sq = 0.f;
    #pragma unroll
    for (int i = 0; i < 4; ++i) {
        float4 v = ((const float4*)src)[lane + i * 64];
        sq += v.x * v.x + v.y * v.y + v.z * v.z + v.w * v.w;
        int p = __builtin_amdgcn_cvt_pk_fp8_f32(v.x, v.y, 0, false);
        p = __builtin_amdgcn_cvt_pk_fp8_f32(v.z, v.w, p, true);
        ((int*)dst)[lane + i * 64] = p;
    }
    #pragma unroll
    for (int off = 32; off; off >>= 1) sq += __shfl_down(sq, off, 64);
    if (lane == 0) { norms[row] = sq; mins[row] = 0x7f7f7f7fu; }
}

// ---------------- fused GEMM + min epilogue + last-block reduction ---------
// Per buffer (24KB): A 128 rows x 64B at +0; B 256 rows x 64B at +8192.
// Rows are 4 x 16B slots, stored slot s holds source slot s ^ (row & 3).
// 3-buffer ring: buf b at b*24576. Tile t uses buf t%3; stages t+2.

#define BUF0 0
#define BUF1 24576
#define BUF2 49152

// A-tile stage: 8KB = exactly 1 gl_lds16/thread. wave covers rows wave*16..+15.
#define STAGE_A(bufB, kcol) do {                                                \
    gl_lds16(Ab + (size_t)(wave * 16 + (lane >> 2)) * DDIM + (kcol)             \
                 + (((lane & 3) ^ ((lane >> 2) & 3)) * 16),                     \
             ldsb + (bufB) + wave * 1024);                                      \
} while (0)

// B-tile stage: 16KB = 2 instrs. instr i covers rows i*128 + wave*16 ..+15.
#define STAGE_B1(bufB, kcol) do {                                               \
    gl_lds16(Bb + (size_t)(wave * 16 + (lane >> 2)) * DDIM + (kcol)             \
                 + (((lane & 3) ^ ((lane >> 2) & 3)) * 16),                     \
             ldsb + (bufB) + 8192 + wave * 1024);                               \
} while (0)
#define STAGE_B2(bufB, kcol) do {                                               \
    gl_lds16(Bb + (size_t)(128 + wave * 16 + (lane >> 2)) * DDIM + (kcol)       \
                 + (((lane & 3) ^ ((lane >> 2) & 3)) * 16),                     \
             ldsb + (bufB) + 8192 + 8192 + wave * 1024);                        \
} while (0)

#define RD_A(CURB, aq) do {                                                     \
    _Pragma("unroll")                                                           \
    for (int fl_ = 0; fl_ < 2; ++fl_) {                                         \
        const int row_ = wr * 64 + (aq) * 32 + fl_ * 16 + r0;                   \
        af[fl_][0] = *(const long*)(ldsb + (CURB) + row_ * 64 + ch0);           \
        af[fl_][1] = *(const long*)(ldsb + (CURB) + row_ * 64 + ch1);           \
    }                                                                           \
} while (0)

#define RD_B(CURB, bq, dst) do {                                                \
    _Pragma("unroll")                                                           \
    for (int fj_ = 0; fj_ < 2; ++fj_) {                                         \
        const int col_ = wc * 64 + (bq) * 32 + fj_ * 16 + r0;                   \
        dst[fj_][0] = *(const long*)(ldsb + (CURB) + 8192 + col_ * 64 + ch0);   \
        dst[fj_][1] = *(const long*)(ldsb + (CURB) + 8192 + col_ * 64 + ch1);   \
    }                                                                           \
} while (0)

#define MFMA_Q(aq, bq, BF)                                                      \
    _Pragma("unroll")                                                           \
    for (int fl_ = 0; fl_ < 2; ++fl_) {                                         \
        _Pragma("unroll")                                                       \
        for (int fj_ = 0; fj_ < 2; ++fj_) {                                     \
            acc[(aq) * 2 + fl_][(bq) * 2 + fj_] =                               \
                __builtin_amdgcn_mfma_f32_16x16x32_fp8_fp8(af[fl_][0], BF[fj_][0], \
                    acc[(aq) * 2 + fl_][(bq) * 2 + fj_], 0, 0, 0);              \
            acc[(aq) * 2 + fl_][(bq) * 2 + fj_] =                               \
                __builtin_amdgcn_mfma_f32_16x16x32_fp8_fp8(af[fl_][1], BF[fj_][1], \
                    acc[(aq) * 2 + fl_][(bq) * 2 + fj_], 0, 0, 0);              \
        }                                                                       \
    }

#define BARRIER_MFMA(aq, bq, BF, WAITSTMT) do {                                 \
    __builtin_amdgcn_s_barrier();                                               \
    asm volatile("s_waitcnt lgkmcnt(0)" ::: "memory");                          \
    __builtin_amdgcn_sched_barrier(0);                                          \
    __builtin_amdgcn_s_setprio(1);                                              \
    MFMA_Q(aq, bq, BF);                                                         \
    __builtin_amdgcn_s_setprio(0);                                              \
    WAITSTMT;                                                                   \
    __builtin_amdgcn_s_barrier();                                               \
} while (0)

#define TILE(t, CURB, NXTB) do {                                                \
    const int kN_ = ((t) + 2) * 64;                                             \
    RD_A(CURB, 0); RD_B(CURB, 0, bf0);                                          \
    if ((t) + 2 < 16) STAGE_A(NXTB, kN_);                                       \
    BARRIER_MFMA(0, 0, bf0, );                                                  \
    RD_B(CURB, 1, bf1);                                                         \
    if ((t) + 2 < 16) STAGE_B1(NXTB, kN_);                                      \
    BARRIER_MFMA(0, 1, bf1, );                                                  \
    RD_A(CURB, 1);                                                              \
    if ((t) + 2 < 16) STAGE_B2(NXTB, kN_);                                      \
    BARRIER_MFMA(1, 1, bf1, );                                                  \
    BARRIER_MFMA(1, 0, bf0,                                                     \
        if ((t) <= 13) { asm volatile("s_waitcnt vmcnt(3)" ::: "memory"); }     \
        else if ((t) == 14) { asm volatile("s_waitcnt vmcnt(0)" ::: "memory"); });\
} while (0)

__global__ __launch_bounds__(512, 4) void cham_gemm_kernel(
    const unsigned char* __restrict__ A,   // set1 fp8 [4096][1024]
    const unsigned char* __restrict__ B,   // set2 fp8 [4096][1024]
    const float* __restrict__ x2, const float* __restrict__ y2,
    unsigned int* __restrict__ mins,   // [8192]: rowmin ++ colmin
    unsigned int* __restrict__ ctr, float* __restrict__ out) {
    __shared__ __align__(16) char lds[73728];
    char* ldsb = lds;
    unsigned int* rowmin = mins;
    unsigned int* colmin = mins + NPTS;

    const int bi = blockIdx.x >> 4;    // 0..31 (128-row tiles)
    const int bj = blockIdx.x & 15;    // 0..15 (256-col tiles)
    const int tid = threadIdx.x;
    const int wave = tid >> 6;
    const int lane = tid & 63;
    const int wr = wave >> 2;          // 0..1 (64 rows each)
    const int wc = wave & 3;           // 0..3 (64 cols each)
    const int r0 = lane & 15;
    const int q = lane >> 4;           // 0..3

    // fragment byte offsets within a 64B row: chunk c = kk*4+q (8B each);
    // stored slot = (c>>1) ^ (r0&3), half = c&1.
    const int ch0 = (((q >> 1) ^ (r0 & 3)) << 4) + ((q & 1) << 3);        // kk=0
    const int ch1 = (((2 + (q >> 1)) ^ (r0 & 3)) << 4) + ((q & 1) << 3);  // kk=1

    const unsigned char* Ab = A + (size_t)(bi * 128) * DDIM;
    const unsigned char* Bb = B + (size_t)(bj * 256) * DDIM;

    f32x4 acc[4][4];
    #pragma unroll
    for (int i = 0; i < 4; ++i)
        #pragma unroll
        for (int j = 0; j < 4; ++j)
            acc[i][j] = (f32x4){0.f, 0.f, 0.f, 0.f};

    long af[2][2], bf0[2][2], bf1[2][2];

    // prologue: stage tiles 0 (buf0) and 1 (buf1); wait tile 0 (3 of 6 left).
    STAGE_A(BUF0, 0); STAGE_B1(BUF0, 0); STAGE_B2(BUF0, 0);
    STAGE_A(BUF1, 64); STAGE_B1(BUF1, 64); STAGE_B2(BUF1, 64);
    asm volatile("s_waitcnt vmcnt(3)" ::: "memory");
    __builtin_amdgcn_s_barrier();

    #pragma unroll 1
    for (int tt = 0; tt < 5; ++tt) {
        const int t3 = 3 * tt;
        TILE(t3 + 0, BUF0, BUF2);
        TILE(t3 + 1, BUF1, BUF0);
        TILE(t3 + 2, BUF2, BUF1);
    }
    TILE(15, BUF0, BUF2);

    // ---- epilogue: dist = (x2[n] + y2[m] - 2*xy)/D, fused row/col mins
    const float invD = 1.0f / (float)DDIM;
    const int nb = bi * 128 + wr * 64;
    const int mb = bj * 256 + wc * 64;

    float y2v[4];
    #pragma unroll
    for (int fj = 0; fj < 4; ++fj) y2v[fj] = y2[mb + fj * 16 + r0];

    float cv[4];
    #pragma unroll
    for (int fj = 0; fj < 4; ++fj) cv[fj] = 3.0e38f;

    #pragma unroll
    for (int fi = 0; fi < 4; ++fi) {
        #pragma unroll
        for (int rg = 0; rg < 4; ++rg) {
            const int n = nb + fi * 16 + q * 4 + rg;
            const float x2v = x2[n];
            float rv = 3.0e38f;
            #pragma unroll
            for (int fj = 0; fj < 4; ++fj) {
                float d = (x2v + y2v[fj] - 2.0f * acc[fi][fj][rg]) * invD;
                rv = fminf(rv, d);
                cv[fj] = fminf(cv[fj], d);
            }
            rv = fminf(rv, __shfl_xor(rv, 1, 64));
            rv = fminf(rv, __shfl_xor(rv, 2, 64));
            rv = fminf(rv, __shfl_xor(rv, 4, 64));
            rv = fminf(rv, __shfl_xor(rv, 8, 64));
            if (r0 == 0) atomicMin(&rowmin[n], __float_as_uint(rv));
        }
    }

    #pragma unroll
    for (int fj = 0; fj < 4; ++fj) {
        float v = cv[fj];
        v = fminf(v, __shfl_xor(v, 16, 64));
        v = fminf(v, __shfl_xor(v, 32, 64));
        if (lane < 16)
            atomicMin(&colmin[mb + fj * 16 + lane], __float_as_uint(v));
    }

    // ---- last block computes the mean (fence-free, R6-validated)
    __syncthreads();
    __shared__ unsigned int lastflag;
    if (tid == 0)
        lastflag = __hip_atomic_fetch_add(&ctr[0], 1u, __ATOMIC_ACQUIRE,
                                          __HIP_MEMORY_SCOPE_AGENT);
    __syncthreads();
    if (lastflag == 511u) {
        float sum = 0.f;
        #pragma unroll
        for (int i = 0; i < 16; ++i)
            sum += __uint_as_float(__hip_atomic_load(&mins[tid + i * 512],
                    __ATOMIC_RELAXED, __HIP_MEMORY_SCOPE_AGENT));
        #pragma unroll
        for (int off = 32; off; off >>= 1) sum += __shfl_down(sum, off, 64);
        float* red = (float*)ldsb;
        if (lane == 0) red[wave] = sum;
        __syncthreads();
        if (tid == 0) {
            float tot = 0.f;
            #pragma unroll
            for (int i = 0; i < 8; ++i) tot += red[i];
            out[0] = tot * (1.0f / 8192.0f);
        }
    }
}

extern "C" void kernel_launch(void* const* d_in, const int* in_sizes, int n_in,
                              void* d_out, int out_size, void* d_ws, size_t ws_size,
                              hipStream_t stream) {
    const float* s1 = (const float*)d_in[0];
    const float* s2 = (const float*)d_in[1];
    char* ws = (char*)d_ws;

    unsigned char* a8  = (unsigned char*)ws;                          //  4 MB
    unsigned char* b8  = (unsigned char*)(ws + 4194304);              //  4 MB
    float* norms       = (float*)(ws + 8388608);                      // 32 KB
    unsigned int* mins = (unsigned int*)(ws + 8388608 + 32768);       // 32 KB
    unsigned int* ctr  = (unsigned int*)(ws + 8388608 + 65536);       //  4 B
    float* out = (float*)d_out;

    prepass_kernel<<<2048, 256, 0, stream>>>(s1, s2, a8, b8, norms, mins, ctr);
    cham_gemm_kernel<<<512, 512, 0, stream>>>(a8, b8, norms, norms + NPTS,
                                              mins, ctr, out);
}